// Round 2
// baseline (1125.770 us; speedup 1.0000x reference)
//
#include <hip/hip_runtime.h>

#define GG 4
#define TT 2048
#define EE 8
#define DD 1024
#define CC 2048

static constexpr long long GTEC = (long long)GG * TT * EE * CC; // 134217728
static constexpr int NROW = GG * TT * EE;                       // 65536 output rows

// workspace layout (floats/ints, 4B units):
//   [0      , 65536)  probs   [g*T+t][e]
//   [65536  , 131072) selc    [(g*E+e)*T + t]  rank+1 (0 = not selected)
//   [131072 , 196608) selg    [(g*E+e)*T + t]  gate value
//   [196608]          zacc    z_loss accumulator
static constexpr int WS_PROBS = 0;
static constexpr int WS_SELC  = 65536;
static constexpr int WS_SELG  = 131072;
static constexpr int WS_ZACC  = 196608;

// ---------------------------------------------------------------------------
// Kernel A: router logits -> softmax probs [G*T, E], z_loss atomic into ws.
// One wave per token; W (8x1024 = 32KB) staged in LDS.
// ---------------------------------------------------------------------------
__global__ __launch_bounds__(256) void router_probs_kernel(
    const float* __restrict__ x, const float* __restrict__ W,
    const float* __restrict__ bias, float* __restrict__ probs,
    float* __restrict__ zacc)
{
    __shared__ float sW[EE * DD];   // 32 KB
    __shared__ float zpart[4];
    for (int i = threadIdx.x; i < EE * DD; i += 256) sW[i] = W[i];
    __syncthreads();

    const int wave = threadIdx.x >> 6;
    const int lane = threadIdx.x & 63;
    const int token = blockIdx.x * 4 + wave;   // grid = GG*TT/4, exact
    const float* xr = x + (long long)token * DD;

    float acc[EE];
#pragma unroll
    for (int e = 0; e < EE; ++e) acc[e] = 0.f;

#pragma unroll 4
    for (int k = lane; k < DD; k += 64) {
        float xv = xr[k];
#pragma unroll
        for (int e = 0; e < EE; ++e)
            acc[e] = fmaf(xv, sW[e * DD + k], acc[e]);
    }

    // butterfly reduce across the 64-lane wave
#pragma unroll
    for (int off = 32; off > 0; off >>= 1) {
#pragma unroll
        for (int e = 0; e < EE; ++e)
            acc[e] += __shfl_xor(acc[e], off, 64);
    }

#pragma unroll
    for (int e = 0; e < EE; ++e) acc[e] += bias[e];

    float m = acc[0];
#pragma unroll
    for (int e = 1; e < EE; ++e) m = fmaxf(m, acc[e]);
    float s = 0.f;
#pragma unroll
    for (int e = 0; e < EE; ++e) s += expf(acc[e] - m);
    float lse = m + logf(s);

    if (lane < EE)
        probs[(long long)token * EE + lane] = expf(acc[lane] - lse);

    if (lane == 0) {
        float zs = 0.f;
#pragma unroll
        for (int e = 0; e < EE; ++e) {
            float d = acc[e] - lse;
            zs = fmaf(d, d, zs);
        }
        zpart[wave] = zs;
    }
    __syncthreads();
    if (threadIdx.x == 0) {
        float zb = (zpart[0] + zpart[1]) + (zpart[2] + zpart[3]);
        atomicAdd(zacc, zb * (1.0f / ((float)GG * TT * EE)));
    }
}

// ---------------------------------------------------------------------------
// Kernel B: one block per (g,e). Bitonic-sort 2048 (prob, token) keys
// descending (ties -> lower token index first), then record the selection
// compactly in ws:  selc[(g*E+e)*T + t] = rank+1, selg[...] = gate.
// No writes to d_out here.
// ---------------------------------------------------------------------------
__global__ __launch_bounds__(1024) void topk_select_kernel(
    const float* __restrict__ probs, int* __restrict__ selc,
    float* __restrict__ selg)
{
    __shared__ unsigned long long keys[TT];   // 16 KB
    const int g = blockIdx.x >> 3;
    const int e = blockIdx.x & 7;
    const int caps[EE] = {512, 512, 256, 256, 128, 128, 128, 128};
    const int cap = caps[e];
    const int base = (g * EE + e) * TT;

    for (int t = threadIdx.x; t < TT; t += 1024) {
        float p = probs[((long long)g * TT + t) * EE + e];
        unsigned int pb = __float_as_uint(p);   // p > 0: uint order == float order
        keys[t] = ((unsigned long long)pb << 32) |
                  (unsigned long long)(0xFFFFFFFFu - (unsigned)t);
    }
    __syncthreads();

    // bitonic sort, descending
    for (int k = 2; k <= TT; k <<= 1) {
        for (int j = k >> 1; j > 0; j >>= 1) {
            for (int v = threadIdx.x; v < TT; v += 1024) {
                int ixj = v ^ j;
                if (ixj > v) {
                    bool desc = ((v & k) == 0);
                    unsigned long long a = keys[v];
                    unsigned long long b = keys[ixj];
                    bool sw = desc ? (a < b) : (a > b);
                    if (sw) { keys[v] = b; keys[ixj] = a; }
                }
            }
            __syncthreads();
        }
    }

    // zero this (g,e) slice of the selection table, then scatter ranks
    for (int t = threadIdx.x; t < TT; t += 1024) selc[base + t] = 0;
    __syncthreads();

    if (threadIdx.x < cap) {
        unsigned long long kk = keys[threadIdx.x];
        int t = (int)(0xFFFFFFFFu - (unsigned)(kk & 0xFFFFFFFFull));
        float gate = __uint_as_float((unsigned)(kk >> 32));
        selc[base + t] = threadIdx.x + 1;
        selg[base + t] = gate;
    }
}

// ---------------------------------------------------------------------------
// Kernel C: fused zero-fill + scatter. One wave per output row (g,t,e):
// writes the full 2048-float dispatch row and 2048-float combine row as
// coalesced float4 (zeros except the selected column). Writes every output
// element every launch -> no memset of d_out needed, poison-safe.
// 1.074 GB of pure streaming writes ~ 175 us at ~6.2 TB/s.
// ---------------------------------------------------------------------------
__global__ __launch_bounds__(256) void fill_outputs_kernel(
    const int* __restrict__ selc, const float* __restrict__ selg,
    const float* __restrict__ zacc, float* __restrict__ out)
{
    const int wid  = (int)((blockIdx.x * 256 + threadIdx.x) >> 6); // row id
    const int lane = threadIdx.x & 63;

    // row = ((g*T + t)*E + e)
    const int e = wid & (EE - 1);
    const int t = (wid >> 3) & (TT - 1);
    const int g = wid >> 14;                   // wid / (T*E)
    const int s = (g * EE + e) * TT + t;

    const int   c1   = selc[s];                // 0 = no selection
    const float gate = selg[s];
    const int   cq   = (c1 - 1) >> 2;          // which float4 holds column c
    const int   cr   = (c1 - 1) & 3;

    float4* drow = (float4*)out + (long long)wid * (CC / 4);
    float4* crow = (float4*)(out + GTEC) + (long long)wid * (CC / 4);

#pragma unroll
    for (int j0 = 0; j0 < CC / 4; j0 += 64) {
        const int j = j0 + lane;
        float4 vd = make_float4(0.f, 0.f, 0.f, 0.f);
        float4 vc = make_float4(0.f, 0.f, 0.f, 0.f);
        if (c1 && j == cq) {
            ((float*)&vd)[cr] = 1.0f;
            ((float*)&vc)[cr] = gate;
        }
        drow[j] = vd;
        crow[j] = vc;
    }

    if (wid == 0 && lane == 0) out[2 * GTEC] = zacc[0];
}

extern "C" void kernel_launch(void* const* d_in, const int* in_sizes, int n_in,
                              void* d_out, int out_size, void* d_ws, size_t ws_size,
                              hipStream_t stream) {
    const float* x    = (const float*)d_in[0];
    const float* W    = (const float*)d_in[1];
    const float* bias = (const float*)d_in[2];
    float* out   = (float*)d_out;
    float* ws    = (float*)d_ws;

    float* probs = ws + WS_PROBS;
    int*   selc  = (int*)(ws + WS_SELC);
    float* selg  = ws + WS_SELG;
    float* zacc  = ws + WS_ZACC;

    // Only 4 bytes of zeroing needed (z_loss accumulator); the output buffer
    // is fully written by fill_outputs_kernel each launch.
    hipMemsetAsync(zacc, 0, sizeof(float), stream);

    router_probs_kernel<<<GG * TT / 4, 256, 0, stream>>>(
        x, W, bias, probs, zacc);

    topk_select_kernel<<<GG * EE, 1024, 0, stream>>>(probs, selc, selg);

    fill_outputs_kernel<<<NROW / 4, 256, 0, stream>>>(selc, selg, zacc, out);
}

// Round 4
// 1118.816 us; speedup vs baseline: 1.0062x; 1.0062x over previous
//
#include <hip/hip_runtime.h>

#define GG 4
#define TT 2048
#define EE 8
#define DD 1024
#define CC 2048

static constexpr long long GTEC = (long long)GG * TT * EE * CC; // 134217728
static constexpr int NROW = GG * TT * EE;                       // 65536 output rows
static constexpr int NBLK_A = GG * TT / 4;                      // 2048 router blocks

// native 16B vector type (usable with __builtin_nontemporal_store, unlike
// HIP's float4 class type)
typedef float vf4 __attribute__((ext_vector_type(4)));

// workspace layout (4-byte units):
//   [0      , 65536)   probs [g*T+t][e]                        (256 KB)
//   [65536  , 196608)  sel   [(g*E+e)*T + t]  packed u64:      (512 KB, 8B-aligned)
//                        hi32 = gate bits, lo32 = rank+1 (0 = not selected)
//   [196608 , 198656)  zpart [2048]  per-router-block z partial (8 KB)
static constexpr int WS_PROBS = 0;
static constexpr int WS_SEL   = 65536;
static constexpr int WS_ZPART = 196608;

// ---------------------------------------------------------------------------
// Kernel A: router logits -> softmax probs [G*T, E]; per-block z partial.
// One wave per token; W (8x1024 = 32KB) staged in LDS, read as float4
// (ds_read_b128: ~4x fewer LDS issues than the scalar version).
// ---------------------------------------------------------------------------
__global__ __launch_bounds__(256) void router_probs_kernel(
    const float* __restrict__ x, const float* __restrict__ W,
    const float* __restrict__ bias, float* __restrict__ probs,
    float* __restrict__ zpart)
{
    __shared__ float sW[EE * DD];   // 32 KB
    __shared__ float zsh[4];
    {
        const vf4* W4 = (const vf4*)W;
        vf4* sW4 = (vf4*)sW;
        for (int i = threadIdx.x; i < EE * DD / 4; i += 256) sW4[i] = W4[i];
    }
    __syncthreads();

    const int wave = threadIdx.x >> 6;
    const int lane = threadIdx.x & 63;
    const int token = blockIdx.x * 4 + wave;   // grid = GG*TT/4, exact
    const vf4* xr4 = (const vf4*)(x + (long long)token * DD);
    const vf4* sW4 = (const vf4*)sW;

    float acc[EE];
#pragma unroll
    for (int e = 0; e < EE; ++e) acc[e] = 0.f;

#pragma unroll
    for (int it = 0; it < 4; ++it) {
        const int k4 = lane + 64 * it;         // float4 index, 0..255
        const vf4 xv = xr4[k4];
#pragma unroll
        for (int e = 0; e < EE; ++e) {
            const vf4 wv = sW4[e * (DD / 4) + k4];
            acc[e] = fmaf(xv.x, wv.x, acc[e]);
            acc[e] = fmaf(xv.y, wv.y, acc[e]);
            acc[e] = fmaf(xv.z, wv.z, acc[e]);
            acc[e] = fmaf(xv.w, wv.w, acc[e]);
        }
    }

    // butterfly reduce across the 64-lane wave
#pragma unroll
    for (int off = 32; off > 0; off >>= 1) {
#pragma unroll
        for (int e = 0; e < EE; ++e)
            acc[e] += __shfl_xor(acc[e], off, 64);
    }

#pragma unroll
    for (int e = 0; e < EE; ++e) acc[e] += bias[e];

    float m = acc[0];
#pragma unroll
    for (int e = 1; e < EE; ++e) m = fmaxf(m, acc[e]);
    float s = 0.f;
#pragma unroll
    for (int e = 0; e < EE; ++e) s += expf(acc[e] - m);
    const float lse = m + logf(s);

    if (lane < EE)
        probs[(long long)token * EE + lane] = expf(acc[lane] - lse);

    if (lane == 0) {
        float zs = 0.f;
#pragma unroll
        for (int e = 0; e < EE; ++e) {
            const float d = acc[e] - lse;
            zs = fmaf(d, d, zs);
        }
        zsh[wave] = zs;
    }
    __syncthreads();
    if (threadIdx.x == 0)
        zpart[blockIdx.x] = (zsh[0] + zsh[1]) + (zsh[2] + zsh[3]);
}

// ---------------------------------------------------------------------------
// Kernel B: one block per (g,e). Bitonic-sort 2048 (prob, token) keys
// descending (ties -> lower token index first). After the sort, position i
// holds a UNIQUE token, so one pass writes sel for all 2048 tokens:
//   sel[s] = (gate_bits << 32) | (i < cap ? i+1 : 0)
// No zero-pass, no extra syncthreads, no d_out writes.
// ---------------------------------------------------------------------------
__global__ __launch_bounds__(1024) void topk_select_kernel(
    const float* __restrict__ probs, unsigned long long* __restrict__ sel)
{
    __shared__ unsigned long long keys[TT];   // 16 KB
    const int g = blockIdx.x >> 3;
    const int e = blockIdx.x & 7;
    const int caps[EE] = {512, 512, 256, 256, 128, 128, 128, 128};
    const int cap = caps[e];
    const int base = (g * EE + e) * TT;

    for (int t = threadIdx.x; t < TT; t += 1024) {
        const float p = probs[((long long)g * TT + t) * EE + e];
        const unsigned int pb = __float_as_uint(p); // p > 0: uint order == float order
        keys[t] = ((unsigned long long)pb << 32) |
                  (unsigned long long)(0xFFFFFFFFu - (unsigned)t);
    }
    __syncthreads();

    // bitonic sort, descending
    for (int k = 2; k <= TT; k <<= 1) {
        for (int j = k >> 1; j > 0; j >>= 1) {
            for (int v = threadIdx.x; v < TT; v += 1024) {
                const int ixj = v ^ j;
                if (ixj > v) {
                    const bool desc = ((v & k) == 0);
                    const unsigned long long a = keys[v];
                    const unsigned long long b = keys[ixj];
                    if (desc ? (a < b) : (a > b)) { keys[v] = b; keys[ixj] = a; }
                }
            }
            __syncthreads();
        }
    }

    // scatter: sorted position i -> unique token t; rank+1 if selected else 0
    for (int i = threadIdx.x; i < TT; i += 1024) {
        const unsigned long long kk = keys[i];
        const int t = (int)(0xFFFFFFFFu - (unsigned)(kk & 0xFFFFFFFFull));
        const unsigned int pb = (unsigned int)(kk >> 32);
        const unsigned int rank1 = (i < cap) ? (unsigned int)(i + 1) : 0u;
        sel[base + t] = ((unsigned long long)pb << 32) | (unsigned long long)rank1;
    }
}

// ---------------------------------------------------------------------------
// Kernel C: fused zero-fill + scatter + z_loss finalize. One wave per output
// row (g,t,e): writes the full 2048-float dispatch row and 2048-float combine
// row as nontemporal 16B stores (zeros except the selected column). Writes
// every output element every launch -> no memset of d_out needed, poison-safe.
// Block 0 / wave 0 additionally reduces the 2048 z partials into out[2*GTEC].
// ---------------------------------------------------------------------------
__global__ __launch_bounds__(256) void fill_outputs_kernel(
    const unsigned long long* __restrict__ sel,
    const float* __restrict__ zpart, float* __restrict__ out)
{
    const int wid  = (int)((blockIdx.x * 256 + threadIdx.x) >> 6); // row id
    const int lane = threadIdx.x & 63;

    // row = ((g*T + t)*E + e)
    const int e = wid & (EE - 1);
    const int t = (wid >> 3) & (TT - 1);
    const int g = wid >> 14;                   // wid / (T*E)

    const unsigned long long sv = sel[(g * EE + e) * TT + t];
    const unsigned int rank1 = (unsigned int)(sv & 0xFFFFFFFFull);
    const float gate = __uint_as_float((unsigned int)(sv >> 32));
    const int cq = ((int)rank1 - 1) >> 2;      // which 16B word holds column c
    const int cr = ((int)rank1 - 1) & 3;

    vf4* drow = (vf4*)out + (long long)wid * (CC / 4);
    vf4* crow = (vf4*)(out + GTEC) + (long long)wid * (CC / 4);

#pragma unroll
    for (int j0 = 0; j0 < CC / 4; j0 += 64) {
        const int j = j0 + lane;
        vf4 vd = (vf4)(0.f);
        vf4 vc = (vf4)(0.f);
        if (rank1 && j == cq) {
            vd[cr] = 1.0f;
            vc[cr] = gate;
        }
        __builtin_nontemporal_store(vd, &drow[j]);
        __builtin_nontemporal_store(vc, &crow[j]);
    }

    // z_loss: block 0, wave 0 reduces the 2048 per-router-block partials
    if (blockIdx.x == 0 && threadIdx.x < 64) {
        float zs = 0.f;
        for (int i = lane; i < NBLK_A; i += 64) zs += zpart[i];
#pragma unroll
        for (int off = 32; off > 0; off >>= 1)
            zs += __shfl_xor(zs, off, 64);
        if (lane == 0)
            out[2 * GTEC] = zs * (1.0f / ((float)GG * TT * EE));
    }
}

extern "C" void kernel_launch(void* const* d_in, const int* in_sizes, int n_in,
                              void* d_out, int out_size, void* d_ws, size_t ws_size,
                              hipStream_t stream) {
    const float* x    = (const float*)d_in[0];
    const float* W    = (const float*)d_in[1];
    const float* bias = (const float*)d_in[2];
    float* out = (float*)d_out;
    float* ws  = (float*)d_ws;

    float* probs = ws + WS_PROBS;
    unsigned long long* sel = (unsigned long long*)(ws + WS_SEL);
    float* zpart = ws + WS_ZPART;

    // No memsets at all: every ws/output word consumed is produced upstream
    // in the same launch. 3 dispatches total.
    router_probs_kernel<<<NBLK_A, 256, 0, stream>>>(x, W, bias, probs, zpart);
    topk_select_kernel<<<GG * EE, 1024, 0, stream>>>(probs, sel);
    fill_outputs_kernel<<<NROW / 4, 256, 0, stream>>>(sel, zpart, out);
}

// Round 5
// 1088.818 us; speedup vs baseline: 1.0339x; 1.0276x over previous
//
#include <hip/hip_runtime.h>

#define GG 4
#define TT 2048
#define EE 8
#define DD 1024
#define CC 2048

static constexpr long long GTEC = (long long)GG * TT * EE * CC; // 134217728
static constexpr int NBLK_A = GG * TT / 4;                      // 2048 router blocks

// native 16B vector type
typedef float vf4 __attribute__((ext_vector_type(4)));

// workspace layout (4-byte units):
//   [0      , 65536)   probs [g*T+t][e]                         (256 KB)
//   [65536  , 67584)   zpart [2048] per-router-block z partials (8 KB)
static constexpr int WS_PROBS = 0;
static constexpr int WS_ZPART = 65536;

// ---------------------------------------------------------------------------
// Kernel A: router logits -> softmax probs [G*T, E]; per-block z partial.
// One wave per token; W (8x1024 = 32KB) staged in LDS, float4 reads
// (ds_read_b128). Writes probs + zpart only (workspace).
// ---------------------------------------------------------------------------
__global__ __launch_bounds__(256) void router_probs_kernel(
    const float* __restrict__ x, const float* __restrict__ W,
    const float* __restrict__ bias, float* __restrict__ probs,
    float* __restrict__ zpart)
{
    __shared__ float sW[EE * DD];   // 32 KB
    __shared__ float zsh[4];
    {
        const vf4* W4 = (const vf4*)W;
        vf4* sW4 = (vf4*)sW;
        for (int i = threadIdx.x; i < EE * DD / 4; i += 256) sW4[i] = W4[i];
    }
    __syncthreads();

    const int wave = threadIdx.x >> 6;
    const int lane = threadIdx.x & 63;
    const int token = blockIdx.x * 4 + wave;   // grid = GG*TT/4, exact
    const vf4* xr4 = (const vf4*)(x + (long long)token * DD);
    const vf4* sW4 = (const vf4*)sW;

    float acc[EE];
#pragma unroll
    for (int e = 0; e < EE; ++e) acc[e] = 0.f;

#pragma unroll
    for (int it = 0; it < 4; ++it) {
        const int k4 = lane + 64 * it;         // float4 index, 0..255
        const vf4 xv = xr4[k4];
#pragma unroll
        for (int e = 0; e < EE; ++e) {
            const vf4 wv = sW4[e * (DD / 4) + k4];
            acc[e] = fmaf(xv.x, wv.x, acc[e]);
            acc[e] = fmaf(xv.y, wv.y, acc[e]);
            acc[e] = fmaf(xv.z, wv.z, acc[e]);
            acc[e] = fmaf(xv.w, wv.w, acc[e]);
        }
    }

    // butterfly reduce across the 64-lane wave
#pragma unroll
    for (int off = 32; off > 0; off >>= 1) {
#pragma unroll
        for (int e = 0; e < EE; ++e)
            acc[e] += __shfl_xor(acc[e], off, 64);
    }

#pragma unroll
    for (int e = 0; e < EE; ++e) acc[e] += bias[e];

    float m = acc[0];
#pragma unroll
    for (int e = 1; e < EE; ++e) m = fmaxf(m, acc[e]);
    float s = 0.f;
#pragma unroll
    for (int e = 0; e < EE; ++e) s += expf(acc[e] - m);
    const float lse = m + logf(s);

    if (lane < EE)
        probs[(long long)token * EE + lane] = expf(acc[lane] - lse);

    if (lane == 0) {
        float zs = 0.f;
#pragma unroll
        for (int e = 0; e < EE; ++e) {
            const float d = acc[e] - lse;
            zs = fmaf(d, d, zs);
        }
        zsh[wave] = zs;
    }
    __syncthreads();
    if (threadIdx.x == 0)
        zpart[blockIdx.x] = (zsh[0] + zsh[1]) + (zsh[2] + zsh[3]);
}

// ---------------------------------------------------------------------------
// Kernel B: one block per (g,e). Bitonic-sort 2048 (prob, token) keys
// descending (ties -> lower token index first), then sparse-scatter the
// selected entries straight into the (already zeroed) output:
//   out[((g*T+t)*E+e)*C + rank]        = 1.0f   (dispatch)
//   out[GTEC + ((g*T+t)*E+e)*C + rank] = gate   (combine)
// Block 0 additionally reduces the 2048 z partials into out[2*GTEC]
// (done by wave 0 up front, independent of the sort).
// ---------------------------------------------------------------------------
__global__ __launch_bounds__(1024) void topk_scatter_kernel(
    const float* __restrict__ probs, const float* __restrict__ zpart,
    float* __restrict__ out)
{
    __shared__ unsigned long long keys[TT];   // 16 KB
    const int g = blockIdx.x >> 3;
    const int e = blockIdx.x & 7;
    const int caps[EE] = {512, 512, 256, 256, 128, 128, 128, 128};
    const int cap = caps[e];

    // z_loss finalize (block 0, wave 0) — independent of the sort below
    if (blockIdx.x == 0 && threadIdx.x < 64) {
        const int lane = threadIdx.x;
        float zs = 0.f;
        for (int i = lane; i < NBLK_A; i += 64) zs += zpart[i];
#pragma unroll
        for (int off = 32; off > 0; off >>= 1)
            zs += __shfl_xor(zs, off, 64);
        if (lane == 0)
            out[2 * GTEC] = zs * (1.0f / ((float)GG * TT * EE));
    }

    for (int t = threadIdx.x; t < TT; t += 1024) {
        const float p = probs[((long long)g * TT + t) * EE + e];
        const unsigned int pb = __float_as_uint(p); // p > 0: uint order == float order
        keys[t] = ((unsigned long long)pb << 32) |
                  (unsigned long long)(0xFFFFFFFFu - (unsigned)t);
    }
    __syncthreads();

    // bitonic sort, descending
    for (int k = 2; k <= TT; k <<= 1) {
        for (int j = k >> 1; j > 0; j >>= 1) {
            for (int v = threadIdx.x; v < TT; v += 1024) {
                const int ixj = v ^ j;
                if (ixj > v) {
                    const bool desc = ((v & k) == 0);
                    const unsigned long long a = keys[v];
                    const unsigned long long b = keys[ixj];
                    if (desc ? (a < b) : (a > b)) { keys[v] = b; keys[ixj] = a; }
                }
            }
            __syncthreads();
        }
    }

    // sparse scatter of the selected (rank < cap) entries
    if (threadIdx.x < cap) {
        const unsigned long long kk = keys[threadIdx.x];
        const int t = (int)(0xFFFFFFFFu - (unsigned)(kk & 0xFFFFFFFFull));
        const float gate = __uint_as_float((unsigned int)(kk >> 32));
        const long long base =
            (((long long)g * TT + t) * EE + e) * CC + threadIdx.x;
        out[base] = 1.0f;            // dispatch_mask (read back as float32)
        out[GTEC + base] = gate;     // combine_array
    }
}

extern "C" void kernel_launch(void* const* d_in, const int* in_sizes, int n_in,
                              void* d_out, int out_size, void* d_ws, size_t ws_size,
                              hipStream_t stream) {
    const float* x    = (const float*)d_in[0];
    const float* W    = (const float*)d_in[1];
    const float* bias = (const float*)d_in[2];
    float* out = (float*)d_out;
    float* ws  = (float*)d_ws;

    float* probs = ws + WS_PROBS;
    float* zpart = ws + WS_ZPART;

    // Zero the output exactly as R0/R1 did (out_size is an ELEMENT count:
    // this call measured 1092-1094 us total and wrote 1.074 GB). The runtime
    // fillBufferAligned achieves ~6.2 TB/s — faster than our dense-fill
    // kernel (R2/R4 were +27-35 us).
    hipMemsetAsync(d_out, 0, (size_t)out_size * sizeof(float), stream);

    router_probs_kernel<<<NBLK_A, 256, 0, stream>>>(x, W, bias, probs, zpart);

    topk_scatter_kernel<<<GG * EE, 1024, 0, stream>>>(probs, zpart, out);
}